// Round 2
// baseline (1299.126 us; speedup 1.0000x reference)
//
#include <hip/hip_runtime.h>

// SlidingWindowPyramidAttention — fp32 reference-exact implementation.
// Shapes: B=4, C=256, H=W=64, ws=8 -> 256 windows, 64 positions each.
// NH=8 heads x HD=32, NL=3 levels, NP=4 points, GN groups=8 (16 ch each).

#define CC   256   // channels
#define CH   128   // hidden (C/2)
#define NHD  8     // heads
#define HDIM 32    // head dim
#define NPT  4     // points
#define NLV  3     // levels
#define SS   64    // spatial positions per window (8x8)
#define LPN  12    // NL*NP
#define NWIN 256   // B * (H/8) * (W/8)

__device__ __forceinline__ int rfl(int x) { return __builtin_amdgcn_readfirstlane(x); }

// ---------------------------------------------------------------------------
// K1: offset + attention-weight heads.
//   per window: LDS qs[256][64] (64KB) + h1[128][64] (32KB) = 96KB
//   outputs: PXY[bw][s][h][lp] (float2 sample coords), A[bw][s][h][lp] (softmaxed)
// ---------------------------------------------------------------------------
__global__ __launch_bounds__(256, 1) void k_heads(
    const float* __restrict__ query,
    const float* __restrict__ so_w1, const float* __restrict__ so_b1,
    const float* __restrict__ so_g,  const float* __restrict__ so_be,
    const float* __restrict__ so_w2, const float* __restrict__ so_b2,
    const float* __restrict__ aw_w1, const float* __restrict__ aw_b1,
    const float* __restrict__ aw_g,  const float* __restrict__ aw_be,
    const float* __restrict__ aw_w2, const float* __restrict__ aw_b2,
    float2* __restrict__ PXY, float* __restrict__ A)
{
    extern __shared__ float lds[];
    float* qs = lds;            // [256][64]
    float* h1 = lds + CC * SS;  // [128][64]

    const int bw = blockIdx.x;
    const int b  = bw >> 6;
    const int wy = (bw >> 3) & 7;
    const int wx = bw & 7;
    const int t  = threadIdx.x;
    const int lane = t & 63;
    const int g = rfl(t >> 6);   // wave id, wave-uniform SGPR

    // ---- stage q window: 2048 (channel,row) pairs, 8 contiguous floats each
    {
        const float* qb = query + (size_t)b * CC * 4096 + wy * 8 * 64 + wx * 8;
        for (int i = t; i < CC * 8; i += 256) {
            int c = i >> 3, r = i & 7;
            const float* src = qb + (size_t)c * 4096 + r * 64;
            float4 v0 = *(const float4*)src;
            float4 v1 = *(const float4*)(src + 4);
            float* dst = qs + c * SS + r * 8;
            *(float4*)dst       = v0;
            *(float4*)(dst + 4) = v1;
        }
    }
    __syncthreads();

    // conv1x1 (256->128) + bias + GroupNorm(8 groups of 16ch x 64sp) + ReLU -> h1
    // wave g owns output channels [g*32, g*32+32) == GN groups 2g, 2g+1 (wave-local stats)
    auto conv1_gn = [&](const float* W1, const float* B1,
                        const float* G,  const float* Be) {
        float acc[32];
        #pragma unroll
        for (int o = 0; o < 32; o++) acc[o] = 0.f;
        const int c2b = g * 32;
        for (int cb = 0; cb < CC; cb += 16) {
            float vreg[16];
            #pragma unroll
            for (int j = 0; j < 16; j++) vreg[j] = qs[(cb + j) * SS + lane];
            #pragma unroll
            for (int o = 0; o < 32; o++) {
                const float* wr = W1 + (size_t)(c2b + o) * CC + cb;
                #pragma unroll
                for (int j = 0; j < 16; j++) acc[o] = fmaf(wr[j], vreg[j], acc[o]);
            }
        }
        float s0 = 0.f, q0 = 0.f, s1 = 0.f, q1 = 0.f;
        #pragma unroll
        for (int o = 0; o < 32; o++) {
            acc[o] += B1[c2b + o];
            if (o < 16) { s0 += acc[o]; q0 += acc[o] * acc[o]; }
            else        { s1 += acc[o]; q1 += acc[o] * acc[o]; }
        }
        #pragma unroll
        for (int off = 1; off < 64; off <<= 1) {
            s0 += __shfl_xor(s0, off, 64);
            q0 += __shfl_xor(q0, off, 64);
            s1 += __shfl_xor(s1, off, 64);
            q1 += __shfl_xor(q1, off, 64);
        }
        const float inv = 1.0f / 1024.0f;
        float mu0 = s0 * inv, va0 = q0 * inv - mu0 * mu0;
        float mu1 = s1 * inv, va1 = q1 * inv - mu1 * mu1;
        float r0 = rsqrtf(va0 + 1e-5f), r1 = rsqrtf(va1 + 1e-5f);
        #pragma unroll
        for (int o = 0; o < 32; o++) {
            int c2 = c2b + o;
            float mu = (o < 16) ? mu0 : mu1;
            float rs = (o < 16) ? r0  : r1;
            float val = (acc[o] - mu) * rs * G[c2] + Be[c2];
            h1[c2 * SS + lane] = fmaxf(val, 0.f);
        }
    };

    // ===================== sampling-offset head =====================
    conv1_gn(so_w1, so_b1, so_g, so_be);
    __syncthreads();
    {
        // conv2: 128 -> 192 ; wave g owns outputs [g*48, g*48+48) (x/y pairs)
        float acc[48];
        #pragma unroll
        for (int i = 0; i < 48; i++) acc[i] = 0.f;
        const int ob = g * 48;
        for (int cb = 0; cb < CH; cb += 16) {
            float vreg[16];
            #pragma unroll
            for (int j = 0; j < 16; j++) vreg[j] = h1[(cb + j) * SS + lane];
            #pragma unroll
            for (int i = 0; i < 48; i++) {
                const float* wr = so_w2 + (size_t)(ob + i) * CH + cb;
                #pragma unroll
                for (int j = 0; j < 16; j++) acc[i] = fmaf(wr[j], vreg[j], acc[i]);
            }
        }
        const int sy = lane >> 3, sx = lane & 7;
        const float refx = sx * (1.f / 7.f), refy = sy * (1.f / 7.f);
        float2* dst = PXY + (size_t)bw * 6144 + lane * 96;
        #pragma unroll
        for (int i = 0; i < 48; i += 2) {
            int o = ob + i;   // o = (h*12+lp)*2 + xy
            float ox = acc[i]     + so_b2[o];
            float oy = acc[i + 1] + so_b2[o + 1];
            float lx = fminf(fmaxf(refx + ox * 0.125f, 0.f), 1.f);
            float ly = fminf(fmaxf(refy + oy * 0.125f, 0.f), 1.f);
            float px = fminf(fmaxf(lx * 8.f - 0.5f, 0.f), 7.f);
            float py = fminf(fmaxf(ly * 8.f - 0.5f, 0.f), 7.f);
            dst[o >> 1] = make_float2(px, py);
        }
    }
    __syncthreads();

    // ===================== attention-weight head =====================
    conv1_gn(aw_w1, aw_b1, aw_g, aw_be);
    __syncthreads();
    {
        // conv2: 128 -> 96 ; wave g owns outputs [g*24, g*24+24) = heads 2g,2g+1
        float acc[24];
        #pragma unroll
        for (int i = 0; i < 24; i++) acc[i] = 0.f;
        const int ob = g * 24;
        for (int cb = 0; cb < CH; cb += 16) {
            float vreg[16];
            #pragma unroll
            for (int j = 0; j < 16; j++) vreg[j] = h1[(cb + j) * SS + lane];
            #pragma unroll
            for (int i = 0; i < 24; i++) {
                const float* wr = aw_w2 + (size_t)(ob + i) * CH + cb;
                #pragma unroll
                for (int j = 0; j < 16; j++) acc[i] = fmaf(wr[j], vreg[j], acc[i]);
            }
        }
        float* dstA = A + (size_t)bw * 6144 + lane * 96 + ob;  // o == h*12+lp
        #pragma unroll
        for (int hh = 0; hh < 2; hh++) {
            float m = -1e30f;
            #pragma unroll
            for (int j = 0; j < 12; j++) {
                acc[hh * 12 + j] += aw_b2[ob + hh * 12 + j];
                m = fmaxf(m, acc[hh * 12 + j]);
            }
            float e[12]; float sum = 0.f;
            #pragma unroll
            for (int j = 0; j < 12; j++) { e[j] = __expf(acc[hh * 12 + j] - m); sum += e[j]; }
            float r = 1.f / sum;
            #pragma unroll
            for (int j = 0; j < 12; j++) dstA[hh * 12 + j] = e[j] * r;
        }
    }
}

// ---------------------------------------------------------------------------
// K2: value projection + bilinear attention + output conv (fused, per window).
//   LDS: vs[256][64] (64KB, reused as attn[c][s]) + Vl[64][260] (65KB, padded)
// ---------------------------------------------------------------------------
__global__ __launch_bounds__(256, 1) void k_attn(
    const float* __restrict__ values,
    const float* __restrict__ vp_w, const float* __restrict__ vp_b,
    const float* __restrict__ op_w, const float* __restrict__ op_b,
    const float* __restrict__ lemb,
    const float2* __restrict__ PXY, const float* __restrict__ A,
    float* __restrict__ outp)
{
    extern __shared__ float lds[];
    float* vs = lds;            // [256][64]  staged values / later attn[c][s]
    float* Vl = lds + CC * SS;  // [64][260]  projected values, row-padded

    const int bw = blockIdx.x;
    const int b  = bw >> 6;
    const int wy = (bw >> 3) & 7;
    const int wx = bw & 7;
    const int t  = threadIdx.x;
    const int lane = t & 63;
    const int g  = rfl(t >> 6);
    const int sq = t >> 2;      // attention: 4 threads per spatial position
    const int dq = t & 3;       // each owns 8 of the 32 head-dims

    float outA[8][8];
    #pragma unroll
    for (int h = 0; h < 8; h++)
        #pragma unroll
        for (int j = 0; j < 8; j++) outA[h][j] = 0.f;

    for (int l = 0; l < NLV; l++) {
        // ---- stage values window + level embed
        const float* vb = values + ((size_t)(b * NLV + l) * CC) * 4096 + wy * 8 * 64 + wx * 8;
        for (int i = t; i < CC * 8; i += 256) {
            int c = i >> 3, r = i & 7;
            const float* src = vb + (size_t)c * 4096 + r * 64;
            float le = lemb[l * CC + c];
            float4 v0 = *(const float4*)src;
            float4 v1 = *(const float4*)(src + 4);
            v0.x += le; v0.y += le; v0.z += le; v0.w += le;
            v1.x += le; v1.y += le; v1.z += le; v1.w += le;
            float* dst = vs + c * SS + r * 8;
            *(float4*)dst       = v0;
            *(float4*)(dst + 4) = v1;
        }
        __syncthreads();

        // ---- vp conv: Vl[s][o] = vp_w[o,:] . vs[:,s] + vp_b[o]
        #pragma unroll
        for (int half = 0; half < 2; half++) {
            const int ob = g * 64 + half * 32;
            float acc[32];
            #pragma unroll
            for (int i = 0; i < 32; i++) acc[i] = vp_b[ob + i];
            for (int cb = 0; cb < CC; cb += 16) {
                float vreg[16];
                #pragma unroll
                for (int j = 0; j < 16; j++) vreg[j] = vs[(cb + j) * SS + lane];
                #pragma unroll
                for (int i = 0; i < 32; i++) {
                    const float* wr = vp_w + (size_t)(ob + i) * CC + cb;
                    #pragma unroll
                    for (int j = 0; j < 16; j++) acc[i] = fmaf(wr[j], vreg[j], acc[i]);
                }
            }
            #pragma unroll
            for (int i = 0; i < 32; i++) Vl[lane * 260 + ob + i] = acc[i];
        }
        __syncthreads();

        // ---- bilinear attention accumulate (ONLY this level's 4 points)
        const float2* pxyp = PXY + (size_t)bw * 6144 + sq * 96;
        const float*  ap   = A   + (size_t)bw * 6144 + sq * 96;
        #pragma unroll
        for (int h = 0; h < 8; h++) {
            const int cb = h * HDIM + dq * 8;
            #pragma unroll
            for (int p = 0; p < NPT; p++) {
                const int lp = l * NPT + p;
                float2 pxy = pxyp[h * 12 + lp];
                float  a   = ap[h * 12 + lp];
                float x0f = floorf(pxy.x), y0f = floorf(pxy.y);
                float fx = pxy.x - x0f, fy = pxy.y - y0f;
                int x0 = (int)x0f, y0 = (int)y0f;
                int x1 = min(x0 + 1, 7), y1 = min(y0 + 1, 7);
                const float4* p00 = (const float4*)(Vl + (y0 * 8 + x0) * 260 + cb);
                const float4* p01 = (const float4*)(Vl + (y0 * 8 + x1) * 260 + cb);
                const float4* p10 = (const float4*)(Vl + (y1 * 8 + x0) * 260 + cb);
                const float4* p11 = (const float4*)(Vl + (y1 * 8 + x1) * 260 + cb);
                float w00 = (1.f - fx) * (1.f - fy), w01 = fx * (1.f - fy);
                float w10 = (1.f - fx) * fy,         w11 = fx * fy;
                float4 a00 = p00[0], q00 = p00[1];
                float4 a01 = p01[0], q01 = p01[1];
                float4 a10 = p10[0], q10 = p10[1];
                float4 a11 = p11[0], q11 = p11[1];
                #define BILC(K, V0, V1, V2, V3) \
                    outA[h][K] = fmaf(a, fmaf(w00, V0, fmaf(w01, V1, fmaf(w10, V2, w11 * V3))), outA[h][K]);
                BILC(0, a00.x, a01.x, a10.x, a11.x)
                BILC(1, a00.y, a01.y, a10.y, a11.y)
                BILC(2, a00.z, a01.z, a10.z, a11.z)
                BILC(3, a00.w, a01.w, a10.w, a11.w)
                BILC(4, q00.x, q01.x, q10.x, q11.x)
                BILC(5, q00.y, q01.y, q10.y, q11.y)
                BILC(6, q00.z, q01.z, q10.z, q11.z)
                BILC(7, q00.w, q01.w, q10.w, q11.w)
                #undef BILC
            }
        }
        __syncthreads();  // Vl readers done before next level's conv overwrites it
    }

    // ---- write attention output to LDS as attn[c][s] (c = h*32 + dq*8 + j)
    #pragma unroll
    for (int h = 0; h < 8; h++)
        #pragma unroll
        for (int j = 0; j < 8; j++)
            vs[(h * HDIM + dq * 8 + j) * SS + sq] = outA[h][j];
    __syncthreads();

    // ---- output conv1x1 (256->256) + window reverse store
    const int sy = lane >> 3, sx = lane & 7;
    float* ob_ptr = outp + (size_t)b * CC * 4096 + wy * 8 * 64 + wx * 8 + sy * 64 + sx;
    #pragma unroll
    for (int half = 0; half < 2; half++) {
        const int ob = g * 64 + half * 32;
        float acc[32];
        #pragma unroll
        for (int i = 0; i < 32; i++) acc[i] = op_b[ob + i];
        for (int cb = 0; cb < CC; cb += 16) {
            float vreg[16];
            #pragma unroll
            for (int j = 0; j < 16; j++) vreg[j] = vs[(cb + j) * SS + lane];
            #pragma unroll
            for (int i = 0; i < 32; i++) {
                const float* wr = op_w + (size_t)(ob + i) * CC + cb;
                #pragma unroll
                for (int j = 0; j < 16; j++) acc[i] = fmaf(wr[j], vreg[j], acc[i]);
            }
        }
        #pragma unroll
        for (int i = 0; i < 32; i++) ob_ptr[(size_t)(ob + i) * 4096] = acc[i];
    }
}

// ---------------------------------------------------------------------------
extern "C" void kernel_launch(void* const* d_in, const int* in_sizes, int n_in,
                              void* d_out, int out_size, void* d_ws, size_t ws_size,
                              hipStream_t stream)
{
    (void)in_sizes; (void)n_in; (void)out_size; (void)ws_size;
    const float* query = (const float*)d_in[0];
    // d_in[1] = keys (unused by reference)
    const float* values = (const float*)d_in[2];
    const float* so_w1 = (const float*)d_in[3];
    const float* so_b1 = (const float*)d_in[4];
    const float* so_g  = (const float*)d_in[5];
    const float* so_be = (const float*)d_in[6];
    const float* so_w2 = (const float*)d_in[7];
    const float* so_b2 = (const float*)d_in[8];
    const float* aw_w1 = (const float*)d_in[9];
    const float* aw_b1 = (const float*)d_in[10];
    const float* aw_g  = (const float*)d_in[11];
    const float* aw_be = (const float*)d_in[12];
    const float* aw_w2 = (const float*)d_in[13];
    const float* aw_b2 = (const float*)d_in[14];
    const float* vp_w  = (const float*)d_in[15];
    const float* vp_b  = (const float*)d_in[16];
    const float* op_w  = (const float*)d_in[17];
    const float* op_b  = (const float*)d_in[18];
    const float* lemb  = (const float*)d_in[19];

    float2* PXY = (float2*)d_ws;
    float*  A   = (float*)((char*)d_ws + (size_t)NWIN * 6144 * sizeof(float2));
    float*  outp = (float*)d_out;

    const int lds1 = (CC * SS + CH * SS) * 4;   // 98304 B
    const int lds2 = (CC * SS + SS * 260) * 4;  // 132096 B
    hipFuncSetAttribute((const void*)k_heads, hipFuncAttributeMaxDynamicSharedMemorySize, lds1);
    hipFuncSetAttribute((const void*)k_attn,  hipFuncAttributeMaxDynamicSharedMemorySize, lds2);

    k_heads<<<dim3(NWIN), dim3(256), lds1, stream>>>(
        query, so_w1, so_b1, so_g, so_be, so_w2, so_b2,
        aw_w1, aw_b1, aw_g, aw_be, aw_w2, aw_b2, PXY, A);
    k_attn<<<dim3(NWIN), dim3(256), lds2, stream>>>(
        values, vp_w, vp_b, op_w, op_b, lemb, PXY, A, outp);
}

// Round 3
// 485.030 us; speedup vs baseline: 2.6784x; 2.6784x over previous
//
#include <hip/hip_runtime.h>

// SlidingWindowPyramidAttention — K1 fp32 VALU (unchanged), K2 bf16-MFMA.
// Shapes: B=4, C=256, H=W=64, ws=8 -> 256 windows, 64 positions each.
// NH=8 heads x HD=32, NL=3 levels, NP=4 points, GN groups=8 (16 ch each).

#define CC   256   // channels
#define CH   128   // hidden (C/2)
#define NHD  8     // heads
#define HDIM 32    // head dim
#define NPT  4     // points
#define NLV  3     // levels
#define SS   64    // spatial positions per window (8x8)
#define LPN  12    // NL*NP
#define NWIN 256   // B * (H/8) * (W/8)

#define VST_PAD 264   // vsT row pitch in bf16 elems (528B, 16B-aligned, 2-way banks)
#define VL_PAD  268   // Vl row pitch in f32 (1072B, 16B-aligned, 2-way banks)

typedef short bf16x8 __attribute__((ext_vector_type(8)));  // 8 bf16 in 4 VGPRs
typedef float f32x4  __attribute__((ext_vector_type(4)));

__device__ __forceinline__ int rfl(int x) { return __builtin_amdgcn_readfirstlane(x); }

__device__ __forceinline__ unsigned short f2bf(float f) {
    unsigned u = __builtin_bit_cast(unsigned, f);
    u += 0x7FFFu + ((u >> 16) & 1u);           // RNE
    return (unsigned short)(u >> 16);
}

__device__ __forceinline__ bf16x8 pack8(const float* v) {
    bf16x8 r;
    #pragma unroll
    for (int i = 0; i < 8; i++) r[i] = (short)f2bf(v[i]);
    return r;
}

// ---------------------------------------------------------------------------
// K1: offset + attention-weight heads (unchanged from round 1, verified).
// ---------------------------------------------------------------------------
__global__ __launch_bounds__(256, 1) void k_heads(
    const float* __restrict__ query,
    const float* __restrict__ so_w1, const float* __restrict__ so_b1,
    const float* __restrict__ so_g,  const float* __restrict__ so_be,
    const float* __restrict__ so_w2, const float* __restrict__ so_b2,
    const float* __restrict__ aw_w1, const float* __restrict__ aw_b1,
    const float* __restrict__ aw_g,  const float* __restrict__ aw_be,
    const float* __restrict__ aw_w2, const float* __restrict__ aw_b2,
    float2* __restrict__ PXY, float* __restrict__ A)
{
    extern __shared__ float lds[];
    float* qs = lds;            // [256][64]
    float* h1 = lds + CC * SS;  // [128][64]

    const int bw = blockIdx.x;
    const int b  = bw >> 6;
    const int wy = (bw >> 3) & 7;
    const int wx = bw & 7;
    const int t  = threadIdx.x;
    const int lane = t & 63;
    const int g = rfl(t >> 6);

    {
        const float* qb = query + (size_t)b * CC * 4096 + wy * 8 * 64 + wx * 8;
        for (int i = t; i < CC * 8; i += 256) {
            int c = i >> 3, r = i & 7;
            const float* src = qb + (size_t)c * 4096 + r * 64;
            float4 v0 = *(const float4*)src;
            float4 v1 = *(const float4*)(src + 4);
            float* dst = qs + c * SS + r * 8;
            *(float4*)dst       = v0;
            *(float4*)(dst + 4) = v1;
        }
    }
    __syncthreads();

    auto conv1_gn = [&](const float* W1, const float* B1,
                        const float* G,  const float* Be) {
        float acc[32];
        #pragma unroll
        for (int o = 0; o < 32; o++) acc[o] = 0.f;
        const int c2b = g * 32;
        for (int cb = 0; cb < CC; cb += 16) {
            float vreg[16];
            #pragma unroll
            for (int j = 0; j < 16; j++) vreg[j] = qs[(cb + j) * SS + lane];
            #pragma unroll
            for (int o = 0; o < 32; o++) {
                const float* wr = W1 + (size_t)(c2b + o) * CC + cb;
                #pragma unroll
                for (int j = 0; j < 16; j++) acc[o] = fmaf(wr[j], vreg[j], acc[o]);
            }
        }
        float s0 = 0.f, q0 = 0.f, s1 = 0.f, q1 = 0.f;
        #pragma unroll
        for (int o = 0; o < 32; o++) {
            acc[o] += B1[c2b + o];
            if (o < 16) { s0 += acc[o]; q0 += acc[o] * acc[o]; }
            else        { s1 += acc[o]; q1 += acc[o] * acc[o]; }
        }
        #pragma unroll
        for (int off = 1; off < 64; off <<= 1) {
            s0 += __shfl_xor(s0, off, 64);
            q0 += __shfl_xor(q0, off, 64);
            s1 += __shfl_xor(s1, off, 64);
            q1 += __shfl_xor(q1, off, 64);
        }
        const float inv = 1.0f / 1024.0f;
        float mu0 = s0 * inv, va0 = q0 * inv - mu0 * mu0;
        float mu1 = s1 * inv, va1 = q1 * inv - mu1 * mu1;
        float r0 = rsqrtf(va0 + 1e-5f), r1 = rsqrtf(va1 + 1e-5f);
        #pragma unroll
        for (int o = 0; o < 32; o++) {
            int c2 = c2b + o;
            float mu = (o < 16) ? mu0 : mu1;
            float rs = (o < 16) ? r0  : r1;
            float val = (acc[o] - mu) * rs * G[c2] + Be[c2];
            h1[c2 * SS + lane] = fmaxf(val, 0.f);
        }
    };

    conv1_gn(so_w1, so_b1, so_g, so_be);
    __syncthreads();
    {
        float acc[48];
        #pragma unroll
        for (int i = 0; i < 48; i++) acc[i] = 0.f;
        const int ob = g * 48;
        for (int cb = 0; cb < CH; cb += 16) {
            float vreg[16];
            #pragma unroll
            for (int j = 0; j < 16; j++) vreg[j] = h1[(cb + j) * SS + lane];
            #pragma unroll
            for (int i = 0; i < 48; i++) {
                const float* wr = so_w2 + (size_t)(ob + i) * CH + cb;
                #pragma unroll
                for (int j = 0; j < 16; j++) acc[i] = fmaf(wr[j], vreg[j], acc[i]);
            }
        }
        const int sy = lane >> 3, sx = lane & 7;
        const float refx = sx * (1.f / 7.f), refy = sy * (1.f / 7.f);
        float2* dst = PXY + (size_t)bw * 6144 + lane * 96;
        #pragma unroll
        for (int i = 0; i < 48; i += 2) {
            int o = ob + i;
            float ox = acc[i]     + so_b2[o];
            float oy = acc[i + 1] + so_b2[o + 1];
            float lx = fminf(fmaxf(refx + ox * 0.125f, 0.f), 1.f);
            float ly = fminf(fmaxf(refy + oy * 0.125f, 0.f), 1.f);
            float px = fminf(fmaxf(lx * 8.f - 0.5f, 0.f), 7.f);
            float py = fminf(fmaxf(ly * 8.f - 0.5f, 0.f), 7.f);
            dst[o >> 1] = make_float2(px, py);
        }
    }
    __syncthreads();

    conv1_gn(aw_w1, aw_b1, aw_g, aw_be);
    __syncthreads();
    {
        float acc[24];
        #pragma unroll
        for (int i = 0; i < 24; i++) acc[i] = 0.f;
        const int ob = g * 24;
        for (int cb = 0; cb < CH; cb += 16) {
            float vreg[16];
            #pragma unroll
            for (int j = 0; j < 16; j++) vreg[j] = h1[(cb + j) * SS + lane];
            #pragma unroll
            for (int i = 0; i < 24; i++) {
                const float* wr = aw_w2 + (size_t)(ob + i) * CH + cb;
                #pragma unroll
                for (int j = 0; j < 16; j++) acc[i] = fmaf(wr[j], vreg[j], acc[i]);
            }
        }
        float* dstA = A + (size_t)bw * 6144 + lane * 96 + ob;
        #pragma unroll
        for (int hh = 0; hh < 2; hh++) {
            float m = -1e30f;
            #pragma unroll
            for (int j = 0; j < 12; j++) {
                acc[hh * 12 + j] += aw_b2[ob + hh * 12 + j];
                m = fmaxf(m, acc[hh * 12 + j]);
            }
            float e[12]; float sum = 0.f;
            #pragma unroll
            for (int j = 0; j < 12; j++) { e[j] = __expf(acc[hh * 12 + j] - m); sum += e[j]; }
            float r = 1.f / sum;
            #pragma unroll
            for (int j = 0; j < 12; j++) dstA[hh * 12 + j] = e[j] * r;
        }
    }
}

// ---------------------------------------------------------------------------
// K2: vp conv (MFMA) + bilinear attention + op conv (MFMA), per window.
//   GEMM form: D[m=o][n=s] = W[o][c] x Act[c][s]
//     A-frag: lane holds W[o = mtile + (lane&15)][c = ks*32 + (lane>>4)*8 + 0..7]
//             (fp32 global, cast to bf16 on the fly)
//     B-frag: lane holds Act[c ...same slice][s = ntile + (lane&15)]
//             from LDS vsT[s][c] bf16, one ds_read_b128
//     D-frag: col(lane&15)=s, row((lane>>4)*4+reg)=o   [guide §3, m89-verified]
//   LDS: vsT bf16 [64][264] (33.8KB) + Vl f32 [64][268] (68.6KB) = 102.4KB
// ---------------------------------------------------------------------------
__global__ __launch_bounds__(256, 1) void k_attn(
    const float* __restrict__ values,
    const float* __restrict__ vp_w, const float* __restrict__ vp_b,
    const float* __restrict__ op_w, const float* __restrict__ op_b,
    const float* __restrict__ lemb,
    const float2* __restrict__ PXY, const float* __restrict__ A,
    float* __restrict__ outp)
{
    extern __shared__ char smem[];
    unsigned short* vsT = (unsigned short*)smem;              // [64][VST_PAD] bf16
    float* Vl = (float*)(smem + SS * VST_PAD * 2);            // [64][VL_PAD] f32

    const int bw = blockIdx.x;
    const int b  = bw >> 6;
    const int wy = (bw >> 3) & 7;
    const int wx = bw & 7;
    const int t  = threadIdx.x;
    const int lane = t & 63;
    const int g  = rfl(t >> 6);
    const int sq = t >> 2;      // gather: 4 threads per spatial position
    const int dq = t & 3;       // each owns 8 of the 32 head-dims

    float outA[8][8];
    #pragma unroll
    for (int h = 0; h < 8; h++)
        #pragma unroll
        for (int j = 0; j < 8; j++) outA[h][j] = 0.f;

    const int srow = (lane >> 3) * 64 + (lane & 7);   // y*64+x for s=lane

    for (int l = 0; l < NLV; l++) {
        // ---- stage vsT[s][c] bf16 (+ level embed); s = lane, wave g does 8 c-groups
        {
            const float* vb = values + ((size_t)(b * NLV + l) * CC) * 4096 + wy * 8 * 64 + wx * 8;
            const float* le = lemb + l * CC;
            for (int it = 0; it < 8; it++) {
                int cg = g * 8 + it;
                float tmp[8];
                #pragma unroll
                for (int j = 0; j < 8; j++) {
                    int c = cg * 8 + j;
                    tmp[j] = vb[(size_t)c * 4096 + srow] + le[c];
                }
                *(bf16x8*)(vsT + lane * VST_PAD + cg * 8) = pack8(tmp);
            }
        }
        __syncthreads();

        // ---- vp GEMM: wave g computes o in [g*64, g*64+64) for all 64 s
        {
            f32x4 acc[4][4];
            #pragma unroll
            for (int mt = 0; mt < 4; mt++)
                #pragma unroll
                for (int nt = 0; nt < 4; nt++)
                    acc[mt][nt] = (f32x4){0.f, 0.f, 0.f, 0.f};

            const int kc = (lane >> 4) * 8;
            for (int ks = 0; ks < 8; ks++) {
                const int c = ks * 32 + kc;
                bf16x8 bf[4];
                #pragma unroll
                for (int nt = 0; nt < 4; nt++) {
                    int s = nt * 16 + (lane & 15);
                    bf[nt] = *(const bf16x8*)(vsT + s * VST_PAD + c);
                }
                #pragma unroll
                for (int mt = 0; mt < 4; mt++) {
                    int o = g * 64 + mt * 16 + (lane & 15);
                    const float* wr = vp_w + (size_t)o * CC + c;
                    float tmp[8];
                    #pragma unroll
                    for (int j = 0; j < 8; j++) tmp[j] = wr[j];
                    bf16x8 af = pack8(tmp);
                    #pragma unroll
                    for (int nt = 0; nt < 4; nt++)
                        acc[mt][nt] = __builtin_amdgcn_mfma_f32_16x16x32_bf16(
                            af, bf[nt], acc[mt][nt], 0, 0, 0);
                }
            }
            // write Vl[s][o] = acc + vp_b[o]
            #pragma unroll
            for (int mt = 0; mt < 4; mt++)
                #pragma unroll
                for (int nt = 0; nt < 4; nt++)
                    #pragma unroll
                    for (int r = 0; r < 4; r++) {
                        int o = g * 64 + mt * 16 + (lane >> 4) * 4 + r;
                        int s = nt * 16 + (lane & 15);
                        Vl[s * VL_PAD + o] = acc[mt][nt][r] + vp_b[o];
                    }
        }
        __syncthreads();

        // ---- bilinear gather for this level's 4 points (fp32, round-1 verified)
        {
            const float2* pxyp = PXY + (size_t)bw * 6144 + sq * 96;
            const float*  ap   = A   + (size_t)bw * 6144 + sq * 96;
            #pragma unroll
            for (int h = 0; h < 8; h++) {
                const int cb = h * HDIM + dq * 8;
                #pragma unroll
                for (int p = 0; p < NPT; p++) {
                    const int lp = l * NPT + p;
                    float2 pxy = pxyp[h * 12 + lp];
                    float  a   = ap[h * 12 + lp];
                    float x0f = floorf(pxy.x), y0f = floorf(pxy.y);
                    float fx = pxy.x - x0f, fy = pxy.y - y0f;
                    int x0 = (int)x0f, y0 = (int)y0f;
                    int x1 = min(x0 + 1, 7), y1 = min(y0 + 1, 7);
                    const float4* p00 = (const float4*)(Vl + (y0 * 8 + x0) * VL_PAD + cb);
                    const float4* p01 = (const float4*)(Vl + (y0 * 8 + x1) * VL_PAD + cb);
                    const float4* p10 = (const float4*)(Vl + (y1 * 8 + x0) * VL_PAD + cb);
                    const float4* p11 = (const float4*)(Vl + (y1 * 8 + x1) * VL_PAD + cb);
                    float w00 = (1.f - fx) * (1.f - fy), w01 = fx * (1.f - fy);
                    float w10 = (1.f - fx) * fy,         w11 = fx * fy;
                    float4 a00 = p00[0], q00 = p00[1];
                    float4 a01 = p01[0], q01 = p01[1];
                    float4 a10 = p10[0], q10 = p10[1];
                    float4 a11 = p11[0], q11 = p11[1];
                    #define BILC(K, V0, V1, V2, V3) \
                        outA[h][K] = fmaf(a, fmaf(w00, V0, fmaf(w01, V1, fmaf(w10, V2, w11 * V3))), outA[h][K]);
                    BILC(0, a00.x, a01.x, a10.x, a11.x)
                    BILC(1, a00.y, a01.y, a10.y, a11.y)
                    BILC(2, a00.z, a01.z, a10.z, a11.z)
                    BILC(3, a00.w, a01.w, a10.w, a11.w)
                    BILC(4, q00.x, q01.x, q10.x, q11.x)
                    BILC(5, q00.y, q01.y, q10.y, q11.y)
                    BILC(6, q00.z, q01.z, q10.z, q11.z)
                    BILC(7, q00.w, q01.w, q10.w, q11.w)
                    #undef BILC
                }
            }
        }
        __syncthreads();   // gather done before next level overwrites vsT/Vl
    }

    // ---- pack attention output into vsT[s][c] bf16 (c = h*32 + dq*8 + j)
    #pragma unroll
    for (int h = 0; h < 8; h++)
        *(bf16x8*)(vsT + sq * VST_PAD + h * HDIM + dq * 8) = pack8(outA[h]);
    __syncthreads();

    // ---- op GEMM (same form) + bias + window-reverse store
    {
        f32x4 acc[4][4];
        #pragma unroll
        for (int mt = 0; mt < 4; mt++)
            #pragma unroll
            for (int nt = 0; nt < 4; nt++)
                acc[mt][nt] = (f32x4){0.f, 0.f, 0.f, 0.f};

        const int kc = (lane >> 4) * 8;
        for (int ks = 0; ks < 8; ks++) {
            const int c = ks * 32 + kc;
            bf16x8 bf[4];
            #pragma unroll
            for (int nt = 0; nt < 4; nt++) {
                int s = nt * 16 + (lane & 15);
                bf[nt] = *(const bf16x8*)(vsT + s * VST_PAD + c);
            }
            #pragma unroll
            for (int mt = 0; mt < 4; mt++) {
                int o = g * 64 + mt * 16 + (lane & 15);
                const float* wr = op_w + (size_t)o * CC + c;
                float tmp[8];
                #pragma unroll
                for (int j = 0; j < 8; j++) tmp[j] = wr[j];
                bf16x8 af = pack8(tmp);
                #pragma unroll
                for (int nt = 0; nt < 4; nt++)
                    acc[mt][nt] = __builtin_amdgcn_mfma_f32_16x16x32_bf16(
                        af, bf[nt], acc[mt][nt], 0, 0, 0);
            }
        }
        const size_t obase = (size_t)b * CC * 4096 + wy * 8 * 64 + wx * 8;
        #pragma unroll
        for (int mt = 0; mt < 4; mt++)
            #pragma unroll
            for (int nt = 0; nt < 4; nt++)
                #pragma unroll
                for (int r = 0; r < 4; r++) {
                    int o = g * 64 + mt * 16 + (lane >> 4) * 4 + r;
                    int s = nt * 16 + (lane & 15);
                    outp[obase + (size_t)o * 4096 + (s >> 3) * 64 + (s & 7)]
                        = acc[mt][nt][r] + op_b[o];
                }
    }
}

// ---------------------------------------------------------------------------
extern "C" void kernel_launch(void* const* d_in, const int* in_sizes, int n_in,
                              void* d_out, int out_size, void* d_ws, size_t ws_size,
                              hipStream_t stream)
{
    (void)in_sizes; (void)n_in; (void)out_size; (void)ws_size;
    const float* query = (const float*)d_in[0];
    // d_in[1] = keys (unused by reference)
    const float* values = (const float*)d_in[2];
    const float* so_w1 = (const float*)d_in[3];
    const float* so_b1 = (const float*)d_in[4];
    const float* so_g  = (const float*)d_in[5];
    const float* so_be = (const float*)d_in[6];
    const float* so_w2 = (const float*)d_in[7];
    const float* so_b2 = (const float*)d_in[8];
    const float* aw_w1 = (const float*)d_in[9];
    const float* aw_b1 = (const float*)d_in[10];
    const float* aw_g  = (const float*)d_in[11];
    const float* aw_be = (const float*)d_in[12];
    const float* aw_w2 = (const float*)d_in[13];
    const float* aw_b2 = (const float*)d_in[14];
    const float* vp_w  = (const float*)d_in[15];
    const float* vp_b  = (const float*)d_in[16];
    const float* op_w  = (const float*)d_in[17];
    const float* op_b  = (const float*)d_in[18];
    const float* lemb  = (const float*)d_in[19];

    float2* PXY = (float2*)d_ws;
    float*  A   = (float*)((char*)d_ws + (size_t)NWIN * 6144 * sizeof(float2));
    float*  outp = (float*)d_out;

    const int lds1 = (CC * SS + CH * SS) * 4;                 // 98304 B
    const int lds2 = SS * VST_PAD * 2 + SS * VL_PAD * 4;      // 102400 B
    hipFuncSetAttribute((const void*)k_heads, hipFuncAttributeMaxDynamicSharedMemorySize, lds1);
    hipFuncSetAttribute((const void*)k_attn,  hipFuncAttributeMaxDynamicSharedMemorySize, lds2);

    k_heads<<<dim3(NWIN), dim3(256), lds1, stream>>>(
        query, so_w1, so_b1, so_g, so_be, so_w2, so_b2,
        aw_w1, aw_b1, aw_g, aw_be, aw_w2, aw_b2, PXY, A);
    k_attn<<<dim3(NWIN), dim3(256), lds2, stream>>>(
        values, vp_w, vp_b, op_w, op_b, lemb, PXY, A, outp);
}

// Round 4
// 104.125 us; speedup vs baseline: 12.4766x; 4.6581x over previous
//
#include <hip/hip_runtime.h>

// SlidingWindowPyramidAttention — all convs bf16-MFMA; weights pre-converted.
// Shapes: B=4, C=256, H=W=64, ws=8 -> 256 windows, 64 positions each.
// NH=8 heads x HD=32, NL=3 levels, NP=4 points, GN groups=8 (16 ch each).
//
// MFMA convention (HW-verified round 3): D[m=o][n=s] = W[o][c] x Act[c][s]
//   A-frag: lane holds W[o = mtile + (lane&15)][c = ks*32 + (lane>>4)*8 + 0..7]
//   B-frag: lane holds Act[same c-slice][s = ntile + (lane&15)]
//   D-frag: col(lane&15)=s, row((lane>>4)*4+r)=o

#define CC   256
#define CH   128
#define NHD  8
#define HDIM 32
#define NPT  4
#define NLV  3
#define SS   64
#define NWIN 256

#define QT_PAD  264   // qT row pitch (bf16)
#define HT_PAD  136   // hT row pitch (bf16)
#define AW_PAD  100   // awS row pitch (f32)
#define VST_PAD 264   // vsT row pitch (bf16)
#define VL_PAD  268   // Vl row pitch (f32)

// bf16 weight pool offsets (elements) inside d_ws after PXY+A
#define W_SO1 0
#define W_AW1 32768
#define W_SO2 65536
#define W_AW2 90112
#define W_VP  102400
#define W_OP  167936
#define W_TOT 233472

typedef short bf16x8 __attribute__((ext_vector_type(8)));
typedef short bf16x4 __attribute__((ext_vector_type(4)));
typedef float f32x4  __attribute__((ext_vector_type(4)));

__device__ __forceinline__ int rfl(int x) { return __builtin_amdgcn_readfirstlane(x); }

__device__ __forceinline__ unsigned short f2bf(float f) {
    unsigned u = __builtin_bit_cast(unsigned, f);
    u += 0x7FFFu + ((u >> 16) & 1u);           // RNE
    return (unsigned short)(u >> 16);
}

__device__ __forceinline__ bf16x8 pack8(const float* v) {
    bf16x8 r;
    #pragma unroll
    for (int i = 0; i < 8; i++) r[i] = (short)f2bf(v[i]);
    return r;
}

// ---------------------------------------------------------------------------
// K0: convert the 6 weight matrices fp32 -> bf16 into the d_ws pool (once per
// launch; idempotent). 114 blocks x 256 threads x 8 elems = 233472.
// ---------------------------------------------------------------------------
struct WPack {
    const float *s0, *s1, *s2, *s3, *s4, *s5;
    unsigned short* d;
};
__global__ __launch_bounds__(256) void k_cvt(WPack p) {
    int i = (blockIdx.x * 256 + threadIdx.x) * 8;
    if (i >= W_TOT) return;
    const float* src; int off;
    if      (i < W_AW1) { src = p.s0; off = W_SO1; }
    else if (i < W_SO2) { src = p.s1; off = W_AW1; }
    else if (i < W_AW2) { src = p.s2; off = W_SO2; }
    else if (i < W_VP)  { src = p.s3; off = W_AW2; }
    else if (i < W_OP)  { src = p.s4; off = W_VP;  }
    else                { src = p.s5; off = W_OP;  }
    const float* s = src + (i - off);
    float4 a = *(const float4*)s;
    float4 b = *(const float4*)(s + 4);
    float tmp[8] = {a.x, a.y, a.z, a.w, b.x, b.y, b.z, b.w};
    *(bf16x8*)(p.d + i) = pack8(tmp);
}

// ---------------------------------------------------------------------------
// K1: offset + attention-weight heads, MFMA.
//   LDS: qT bf16[64][264] 33.8KB + hTso/hTaw bf16[64][136] 17.4KB x2
//        + awS f32[64][100] 25.6KB  = 94208 B
// ---------------------------------------------------------------------------
__global__ __launch_bounds__(256, 1) void k_heads(
    const float* __restrict__ query,
    const unsigned short* __restrict__ wso1, const float* __restrict__ so_b1,
    const float* __restrict__ so_g,  const float* __restrict__ so_be,
    const unsigned short* __restrict__ wso2, const float* __restrict__ so_b2,
    const unsigned short* __restrict__ waw1, const float* __restrict__ aw_b1,
    const float* __restrict__ aw_g,  const float* __restrict__ aw_be,
    const unsigned short* __restrict__ waw2, const float* __restrict__ aw_b2,
    float2* __restrict__ PXY, float* __restrict__ A)
{
    extern __shared__ char smem[];
    unsigned short* qT   = (unsigned short*)smem;                       // [64][264]
    unsigned short* hTso = (unsigned short*)(smem + SS * QT_PAD * 2);   // [64][136]
    unsigned short* hTaw = hTso + SS * HT_PAD;                          // [64][136]
    float* awS = (float*)(smem + SS * QT_PAD * 2 + 2 * SS * HT_PAD * 2);// [64][100]

    const int bw = blockIdx.x;
    const int b  = bw >> 6;
    const int wy = (bw >> 3) & 7;
    const int wx = bw & 7;
    const int t  = threadIdx.x;
    const int lane = t & 63;
    const int g  = rfl(t >> 6);
    const int kc = (lane >> 4) * 8;
    const int srow = (lane >> 3) * 64 + (lane & 7);   // y*64+x for s=lane

    // ---- stage qT[s][c] bf16; s = lane, wave g covers channels [g*64, g*64+64)
    {
        const float* qb = query + (size_t)b * CC * 4096 + wy * 8 * 64 + wx * 8;
        for (int it = 0; it < 8; it++) {
            int cg = g * 8 + it;
            float tmp[8];
            #pragma unroll
            for (int j = 0; j < 8; j++)
                tmp[j] = qb[(size_t)(cg * 8 + j) * 4096 + srow];
            *(bf16x8*)(qT + lane * QT_PAD + cg * 8) = pack8(tmp);
        }
    }
    __syncthreads();

    // ---- dual conv1 GEMM (both heads share B-frags); wave g -> rows [g*32,+32)
    f32x4 accS[2][4], accA[2][4];
    #pragma unroll
    for (int mt = 0; mt < 2; mt++)
        #pragma unroll
        for (int nt = 0; nt < 4; nt++) {
            accS[mt][nt] = (f32x4){0.f, 0.f, 0.f, 0.f};
            accA[mt][nt] = (f32x4){0.f, 0.f, 0.f, 0.f};
        }
    for (int ks = 0; ks < 8; ks++) {
        const int c = ks * 32 + kc;
        bf16x8 bq[4];
        #pragma unroll
        for (int nt = 0; nt < 4; nt++)
            bq[nt] = *(const bf16x8*)(qT + (nt * 16 + (lane & 15)) * QT_PAD + c);
        #pragma unroll
        for (int mt = 0; mt < 2; mt++) {
            const int o = g * 32 + mt * 16 + (lane & 15);
            bf16x8 aS = *(const bf16x8*)(wso1 + (size_t)o * CC + c);
            bf16x8 aA = *(const bf16x8*)(waw1 + (size_t)o * CC + c);
            #pragma unroll
            for (int nt = 0; nt < 4; nt++) {
                accS[mt][nt] = __builtin_amdgcn_mfma_f32_16x16x32_bf16(aS, bq[nt], accS[mt][nt], 0, 0, 0);
                accA[mt][nt] = __builtin_amdgcn_mfma_f32_16x16x32_bf16(aA, bq[nt], accA[mt][nt], 0, 0, 0);
            }
        }
    }

    // ---- GN(+bias,ReLU) in D-layout; wave g's mtile mt == GN group 2g+mt
    auto gn_store = [&](f32x4 (&acc)[2][4], const float* B1, const float* G,
                        const float* Be, unsigned short* hT) {
        #pragma unroll
        for (int mt = 0; mt < 2; mt++) {
            const int c2b = g * 32 + mt * 16 + ((lane >> 4) << 2);
            float4 bv = *(const float4*)(B1 + c2b);
            float s = 0.f, q = 0.f;
            #pragma unroll
            for (int nt = 0; nt < 4; nt++)
                #pragma unroll
                for (int r = 0; r < 4; r++) {
                    float v = acc[mt][nt][r] + ((const float*)&bv)[r];
                    acc[mt][nt][r] = v;
                    s += v; q += v * v;
                }
            #pragma unroll
            for (int off = 1; off < 64; off <<= 1) {
                s += __shfl_xor(s, off, 64);
                q += __shfl_xor(q, off, 64);
            }
            const float mu = s * (1.f / 1024.f);
            const float rs = rsqrtf(q * (1.f / 1024.f) - mu * mu + 1e-5f);
            float4 Gv  = *(const float4*)(G + c2b);
            float4 Bev = *(const float4*)(Be + c2b);
            #pragma unroll
            for (int nt = 0; nt < 4; nt++) {
                int ss = nt * 16 + (lane & 15);
                bf16x4 pk;
                #pragma unroll
                for (int r = 0; r < 4; r++) {
                    float val = (acc[mt][nt][r] - mu) * rs * ((const float*)&Gv)[r]
                                + ((const float*)&Bev)[r];
                    pk[r] = (short)f2bf(fmaxf(val, 0.f));
                }
                *(bf16x4*)(hT + ss * HT_PAD + c2b) = pk;
            }
        }
    };
    gn_store(accS, so_b1, so_g, so_be, hTso);
    gn_store(accA, aw_b1, aw_g, aw_be, hTaw);
    __syncthreads();

    // ---- conv2-so (128->192): wave g -> rows [g*48,+48) ; epilogue -> PXY
    {
        f32x4 acc2[3][4];
        #pragma unroll
        for (int mt = 0; mt < 3; mt++)
            #pragma unroll
            for (int nt = 0; nt < 4; nt++) acc2[mt][nt] = (f32x4){0.f, 0.f, 0.f, 0.f};
        for (int ks = 0; ks < 4; ks++) {
            const int c = ks * 32 + kc;
            bf16x8 bh[4];
            #pragma unroll
            for (int nt = 0; nt < 4; nt++)
                bh[nt] = *(const bf16x8*)(hTso + (nt * 16 + (lane & 15)) * HT_PAD + c);
            #pragma unroll
            for (int mt = 0; mt < 3; mt++) {
                const int o = g * 48 + mt * 16 + (lane & 15);
                bf16x8 af = *(const bf16x8*)(wso2 + (size_t)o * CH + c);
                #pragma unroll
                for (int nt = 0; nt < 4; nt++)
                    acc2[mt][nt] = __builtin_amdgcn_mfma_f32_16x16x32_bf16(af, bh[nt], acc2[mt][nt], 0, 0, 0);
            }
        }
        #pragma unroll
        for (int mt = 0; mt < 3; mt++) {
            const int o_base = g * 48 + mt * 16 + ((lane >> 4) << 2);  // mult of 4
            float4 sb = *(const float4*)(so_b2 + o_base);
            #pragma unroll
            for (int nt = 0; nt < 4; nt++) {
                const int s = nt * 16 + (lane & 15);
                const float refx = (s & 7) * (1.f / 7.f);
                const float refy = (s >> 3) * (1.f / 7.f);
                auto mkp = [](float refc, float oc) {
                    float lc = fminf(fmaxf(refc + oc * 0.125f, 0.f), 1.f);
                    return fminf(fmaxf(lc * 8.f - 0.5f, 0.f), 7.f);
                };
                float4 out4;
                out4.x = mkp(refx, acc2[mt][nt][0] + sb.x);
                out4.y = mkp(refy, acc2[mt][nt][1] + sb.y);
                out4.z = mkp(refx, acc2[mt][nt][2] + sb.z);
                out4.w = mkp(refy, acc2[mt][nt][3] + sb.w);
                *(float4*)(PXY + (size_t)bw * 6144 + s * 96 + (o_base >> 1)) = out4;
            }
        }
    }

    // ---- conv2-aw (128->96): 6 mtiles over 4 waves; logits+bias -> awS
    {
        for (int mm = 0; mm < 2; mm++) {
            const int mtile = g + mm * 4;
            if (mtile >= 6) break;   // wave-uniform
            f32x4 acc3[4];
            #pragma unroll
            for (int nt = 0; nt < 4; nt++) acc3[nt] = (f32x4){0.f, 0.f, 0.f, 0.f};
            for (int ks = 0; ks < 4; ks++) {
                const int c = ks * 32 + kc;
                const int o = mtile * 16 + (lane & 15);
                bf16x8 af = *(const bf16x8*)(waw2 + (size_t)o * CH + c);
                #pragma unroll
                for (int nt = 0; nt < 4; nt++) {
                    bf16x8 bh = *(const bf16x8*)(hTaw + (nt * 16 + (lane & 15)) * HT_PAD + c);
                    acc3[nt] = __builtin_amdgcn_mfma_f32_16x16x32_bf16(af, bh, acc3[nt], 0, 0, 0);
                }
            }
            const int o_base = mtile * 16 + ((lane >> 4) << 2);
            float4 ab = *(const float4*)(aw_b2 + o_base);
            #pragma unroll
            for (int nt = 0; nt < 4; nt++) {
                const int s = nt * 16 + (lane & 15);
                float4 o4;
                o4.x = acc3[nt][0] + ab.x;
                o4.y = acc3[nt][1] + ab.y;
                o4.z = acc3[nt][2] + ab.z;
                o4.w = acc3[nt][3] + ab.w;
                *(float4*)(awS + s * AW_PAD + o_base) = o4;
            }
        }
    }
    __syncthreads();

    // ---- softmax over 12 (l,p) per (s,h): 512 tasks
    for (int task = t; task < 512; task += 256) {
        const int s = task >> 3, h = task & 7;
        const float* row = awS + s * AW_PAD + h * 12;
        float4 r0 = *(const float4*)row;
        float4 r1 = *(const float4*)(row + 4);
        float4 r2 = *(const float4*)(row + 8);
        float v[12] = {r0.x, r0.y, r0.z, r0.w, r1.x, r1.y, r1.z, r1.w,
                       r2.x, r2.y, r2.z, r2.w};
        float m = v[0];
        #pragma unroll
        for (int j = 1; j < 12; j++) m = fmaxf(m, v[j]);
        float sum = 0.f;
        #pragma unroll
        for (int j = 0; j < 12; j++) { v[j] = __expf(v[j] - m); sum += v[j]; }
        float rinv = 1.f / sum;
        float* dst = A + (size_t)bw * 6144 + s * 96 + h * 12;
        float4 w0 = {v[0] * rinv, v[1] * rinv, v[2] * rinv, v[3] * rinv};
        float4 w1 = {v[4] * rinv, v[5] * rinv, v[6] * rinv, v[7] * rinv};
        float4 w2 = {v[8] * rinv, v[9] * rinv, v[10] * rinv, v[11] * rinv};
        *(float4*)dst = w0;
        *(float4*)(dst + 4) = w1;
        *(float4*)(dst + 8) = w2;
    }
}

// ---------------------------------------------------------------------------
// K2: vp conv (MFMA) + bilinear attention + op conv (MFMA), per window.
//   Same as round 3 except A-frags load preconverted bf16 weights.
//   LDS: vsT bf16 [64][264] 33.8KB + Vl f32 [64][268] 68.6KB = 102400 B
// ---------------------------------------------------------------------------
__global__ __launch_bounds__(256, 1) void k_attn(
    const float* __restrict__ values,
    const unsigned short* __restrict__ wvp, const float* __restrict__ vp_b,
    const unsigned short* __restrict__ wop, const float* __restrict__ op_b,
    const float* __restrict__ lemb,
    const float2* __restrict__ PXY, const float* __restrict__ A,
    float* __restrict__ outp)
{
    extern __shared__ char smem[];
    unsigned short* vsT = (unsigned short*)smem;              // [64][VST_PAD] bf16
    float* Vl = (float*)(smem + SS * VST_PAD * 2);            // [64][VL_PAD] f32

    const int bw = blockIdx.x;
    const int b  = bw >> 6;
    const int wy = (bw >> 3) & 7;
    const int wx = bw & 7;
    const int t  = threadIdx.x;
    const int lane = t & 63;
    const int g  = rfl(t >> 6);
    const int sq = t >> 2;
    const int dq = t & 3;
    const int kc = (lane >> 4) * 8;

    float outA[8][8];
    #pragma unroll
    for (int h = 0; h < 8; h++)
        #pragma unroll
        for (int j = 0; j < 8; j++) outA[h][j] = 0.f;

    const int srow = (lane >> 3) * 64 + (lane & 7);

    for (int l = 0; l < NLV; l++) {
        {
            const float* vb = values + ((size_t)(b * NLV + l) * CC) * 4096 + wy * 8 * 64 + wx * 8;
            const float* le = lemb + l * CC;
            for (int it = 0; it < 8; it++) {
                int cg = g * 8 + it;
                float tmp[8];
                #pragma unroll
                for (int j = 0; j < 8; j++) {
                    int c = cg * 8 + j;
                    tmp[j] = vb[(size_t)c * 4096 + srow] + le[c];
                }
                *(bf16x8*)(vsT + lane * VST_PAD + cg * 8) = pack8(tmp);
            }
        }
        __syncthreads();

        // ---- vp GEMM: wave g computes o in [g*64, g*64+64) for all 64 s
        {
            f32x4 acc[4][4];
            #pragma unroll
            for (int mt = 0; mt < 4; mt++)
                #pragma unroll
                for (int nt = 0; nt < 4; nt++)
                    acc[mt][nt] = (f32x4){0.f, 0.f, 0.f, 0.f};

            for (int ks = 0; ks < 8; ks++) {
                const int c = ks * 32 + kc;
                bf16x8 bf[4];
                #pragma unroll
                for (int nt = 0; nt < 4; nt++) {
                    int s = nt * 16 + (lane & 15);
                    bf[nt] = *(const bf16x8*)(vsT + s * VST_PAD + c);
                }
                #pragma unroll
                for (int mt = 0; mt < 4; mt++) {
                    int o = g * 64 + mt * 16 + (lane & 15);
                    bf16x8 af = *(const bf16x8*)(wvp + (size_t)o * CC + c);
                    #pragma unroll
                    for (int nt = 0; nt < 4; nt++)
                        acc[mt][nt] = __builtin_amdgcn_mfma_f32_16x16x32_bf16(
                            af, bf[nt], acc[mt][nt], 0, 0, 0);
                }
            }
            #pragma unroll
            for (int mt = 0; mt < 4; mt++)
                #pragma unroll
                for (int nt = 0; nt < 4; nt++)
                    #pragma unroll
                    for (int r = 0; r < 4; r++) {
                        int o = g * 64 + mt * 16 + (lane >> 4) * 4 + r;
                        int s = nt * 16 + (lane & 15);
                        Vl[s * VL_PAD + o] = acc[mt][nt][r] + vp_b[o];
                    }
        }
        __syncthreads();

        // ---- bilinear gather for this level's 4 points (fp32, verified)
        {
            const float2* pxyp = PXY + (size_t)bw * 6144 + sq * 96;
            const float*  ap   = A   + (size_t)bw * 6144 + sq * 96;
            #pragma unroll
            for (int h = 0; h < 8; h++) {
                const int cb = h * HDIM + dq * 8;
                #pragma unroll
                for (int p = 0; p < NPT; p++) {
                    const int lp = l * NPT + p;
                    float2 pxy = pxyp[h * 12 + lp];
                    float  a   = ap[h * 12 + lp];
                    float x0f = floorf(pxy.x), y0f = floorf(pxy.y);
                    float fx = pxy.x - x0f, fy = pxy.y - y0f;
                    int x0 = (int)x0f, y0 = (int)y0f;
                    int x1 = min(x0 + 1, 7), y1 = min(y0 + 1, 7);
                    const float4* p00 = (const float4*)(Vl + (y0 * 8 + x0) * VL_PAD + cb);
                    const float4* p01 = (const float4*)(Vl + (y0 * 8 + x1) * VL_PAD + cb);
                    const float4* p10 = (const float4*)(Vl + (y1 * 8 + x0) * VL_PAD + cb);
                    const float4* p11 = (const float4*)(Vl + (y1 * 8 + x1) * VL_PAD + cb);
                    float w00 = (1.f - fx) * (1.f - fy), w01 = fx * (1.f - fy);
                    float w10 = (1.f - fx) * fy,         w11 = fx * fy;
                    float4 a00 = p00[0], q00 = p00[1];
                    float4 a01 = p01[0], q01 = p01[1];
                    float4 a10 = p10[0], q10 = p10[1];
                    float4 a11 = p11[0], q11 = p11[1];
                    #define BILC(K, V0, V1, V2, V3) \
                        outA[h][K] = fmaf(a, fmaf(w00, V0, fmaf(w01, V1, fmaf(w10, V2, w11 * V3))), outA[h][K]);
                    BILC(0, a00.x, a01.x, a10.x, a11.x)
                    BILC(1, a00.y, a01.y, a10.y, a11.y)
                    BILC(2, a00.z, a01.z, a10.z, a11.z)
                    BILC(3, a00.w, a01.w, a10.w, a11.w)
                    BILC(4, q00.x, q01.x, q10.x, q11.x)
                    BILC(5, q00.y, q01.y, q10.y, q11.y)
                    BILC(6, q00.z, q01.z, q10.z, q11.z)
                    BILC(7, q00.w, q01.w, q10.w, q11.w)
                    #undef BILC
                }
            }
        }
        __syncthreads();
    }

    // ---- pack attention output into vsT[s][c] bf16 (c = h*32 + dq*8 + j)
    #pragma unroll
    for (int h = 0; h < 8; h++)
        *(bf16x8*)(vsT + sq * VST_PAD + h * HDIM + dq * 8) = pack8(outA[h]);
    __syncthreads();

    // ---- op GEMM + bias + window-reverse store
    {
        f32x4 acc[4][4];
        #pragma unroll
        for (int mt = 0; mt < 4; mt++)
            #pragma unroll
            for (int nt = 0; nt < 4; nt++)
                acc[mt][nt] = (f32x4){0.f, 0.f, 0.f, 0.f};

        for (int ks = 0; ks < 8; ks++) {
            const int c = ks * 32 + kc;
            bf16x8 bf[4];
            #pragma unroll
            for (int nt = 0; nt < 4; nt++) {
                int s = nt * 16 + (lane & 15);
                bf[nt] = *(const bf16x8*)(vsT + s * VST_PAD + c);
            }
            #pragma unroll
            for (int mt = 0; mt < 4; mt++) {
                int o = g * 64 + mt * 16 + (lane & 15);
                bf16x8 af = *(const bf16x8*)(wop + (size_t)o * CC + c);
                #pragma unroll
                for (int nt = 0; nt < 4; nt++)
                    acc[mt][nt] = __builtin_amdgcn_mfma_f32_16x16x32_bf16(
                        af, bf[nt], acc[mt][nt], 0, 0, 0);
            }
        }
        const size_t obase = (size_t)b * CC * 4096 + wy * 8 * 64 + wx * 8;
        #pragma unroll
        for (int mt = 0; mt < 4; mt++)
            #pragma unroll
            for (int nt = 0; nt < 4; nt++)
                #pragma unroll
                for (int r = 0; r < 4; r++) {
                    int o = g * 64 + mt * 16 + (lane >> 4) * 4 + r;
                    int s = nt * 16 + (lane & 15);
                    outp[obase + (size_t)o * 4096 + (s >> 3) * 64 + (s & 7)]
                        = acc[mt][nt][r] + op_b[o];
                }
    }
}

// ---------------------------------------------------------------------------
extern "C" void kernel_launch(void* const* d_in, const int* in_sizes, int n_in,
                              void* d_out, int out_size, void* d_ws, size_t ws_size,
                              hipStream_t stream)
{
    (void)in_sizes; (void)n_in; (void)out_size; (void)ws_size;
    const float* query = (const float*)d_in[0];
    // d_in[1] = keys (unused by reference)
    const float* values = (const float*)d_in[2];
    const float* so_w1 = (const float*)d_in[3];
    const float* so_b1 = (const float*)d_in[4];
    const float* so_g  = (const float*)d_in[5];
    const float* so_be = (const float*)d_in[6];
    const float* so_w2 = (const float*)d_in[7];
    const float* so_b2 = (const float*)d_in[8];
    const float* aw_w1 = (const float*)d_in[9];
    const float* aw_b1 = (const float*)d_in[10];
    const float* aw_g  = (const float*)d_in[11];
    const float* aw_be = (const float*)d_in[12];
    const float* aw_w2 = (const float*)d_in[13];
    const float* aw_b2 = (const float*)d_in[14];
    const float* vp_w  = (const float*)d_in[15];
    const float* vp_b  = (const float*)d_in[16];
    const float* op_w  = (const float*)d_in[17];
    const float* op_b  = (const float*)d_in[18];
    const float* lemb  = (const float*)d_in[19];

    float2* PXY = (float2*)d_ws;
    float*  A   = (float*)((char*)d_ws + (size_t)NWIN * 6144 * sizeof(float2));
    unsigned short* WB = (unsigned short*)((char*)d_ws
                        + (size_t)NWIN * 6144 * (sizeof(float2) + sizeof(float)));
    float* outp = (float*)d_out;

    // K0: weight conversion
    WPack p = {so_w1, aw_w1, so_w2, aw_w2, vp_w, op_w, WB};
    k_cvt<<<dim3((W_TOT / 8 + 255) / 256), dim3(256), 0, stream>>>(p);

    const int lds1 = SS * QT_PAD * 2 + 2 * SS * HT_PAD * 2 + SS * AW_PAD * 4; // 94208
    const int lds2 = SS * VST_PAD * 2 + SS * VL_PAD * 4;                      // 102400
    hipFuncSetAttribute((const void*)k_heads, hipFuncAttributeMaxDynamicSharedMemorySize, lds1);
    hipFuncSetAttribute((const void*)k_attn,  hipFuncAttributeMaxDynamicSharedMemorySize, lds2);

    k_heads<<<dim3(NWIN), dim3(256), lds1, stream>>>(
        query, WB + W_SO1, so_b1, so_g, so_be, WB + W_SO2, so_b2,
        WB + W_AW1, aw_b1, aw_g, aw_be, WB + W_AW2, aw_b2, PXY, A);
    k_attn<<<dim3(NWIN), dim3(256), lds2, stream>>>(
        values, WB + W_VP, vp_b, WB + W_OP, op_b, lemb, PXY, A, outp);
}